// Round 3
// baseline (222.902 us; speedup 1.0000x reference)
//
#include <hip/hip_runtime.h>
#include <stdint.h>

// AttentionGate, MI355X gfx950 — R3: single-barrier full-depth staging.
//
// R2 post-mortem: attgate_psi 72 us, 134 MB at 1.9 TB/s effective, MfmaUtil 9%,
// VALUBusy 14% -> latency-bound. Cause: 8 barrier-separated staging bursts
// (prefetch depth 1) with ~2 blocks/CU -> HBM duty-cycle gaps.
// R3: whole A-panel (64 px x 256 ch x 2 tensors) staged to LDS as bf16 in ONE
// burst (64 independent loads/thread, fully unrolled -> max MLP), ONE barrier,
// then all 8 K-iters of MFMA barrier-free (B fragments L2-hot from workspace).
// LDS row stride 264 shorts (132 dw = 4 mod 32): ds_write_b128 conflict-free,
// fragment reads ~2-way (free per m136). 66 KiB LDS -> 2 blocks/CU.
// Epilogue (bias+relu+LN+psi+sigmoid via 3 reductions) unchanged from R2.
//
// gate_mul: out = psi * x, pure grid-stride float4 streaming.
// Prepass wconv: Wx,Wg fp32 -> bf16 fragment-chunk layout [it][n][32k].

typedef __bf16 bf16x8 __attribute__((ext_vector_type(8)));
typedef float f32x4 __attribute__((ext_vector_type(4)));

#define STR2 264          // LDS px-row stride in shorts (528 B; 132 dw = 4 mod 32)
#define LN_EPS 1e-5f

__device__ __forceinline__ uint16_t f2b(float f) {
    union { float f; uint32_t i; } v; v.f = f;
    uint32_t x = v.i;
    return (uint16_t)((x + 0x7FFFu + ((x >> 16) & 1u)) >> 16);  // RNE
}

struct EpiShared {
    float red[3][4][64];   // s, ss, t partials: [value][out-slice][pixel]
    float cpart[8];        // per-wave partials: sumA (0..3), sumB (4..7)
};

union ALds {
    uint16_t a[2][64 * STR2];   // [tensor: 0=x 1=g][px*STR2 + ch]  66 KiB
    EpiShared e;
};

// ---- prepass: W fp32 -> bf16 chunk layout: dst[it*8192 + n*32 + kk] = W[n][it*32+kk]
__global__ void wconv_kernel(const float* __restrict__ Wx, const float* __restrict__ Wg,
                             uint16_t* __restrict__ ox, uint16_t* __restrict__ og) {
    const int i  = blockIdx.x * 256 + threadIdx.x;   // 64 blocks -> 16384
    const int n  = i >> 6;
    const int k4 = (i & 63) * 4;
    const int it = k4 >> 5;
    const int kk = k4 & 31;
    const int dst = it * 8192 + n * 32 + kk;
    const float4 a = *(const float4*)&Wx[n * 256 + k4];
    const float4 b = *(const float4*)&Wg[n * 256 + k4];
    uint2 pa, pb;
    pa.x = (uint32_t)f2b(a.x) | ((uint32_t)f2b(a.y) << 16);
    pa.y = (uint32_t)f2b(a.z) | ((uint32_t)f2b(a.w) << 16);
    pb.x = (uint32_t)f2b(b.x) | ((uint32_t)f2b(b.y) << 16);
    pb.y = (uint32_t)f2b(b.z) | ((uint32_t)f2b(b.w) << 16);
    *(uint2*)&ox[dst] = pa;
    *(uint2*)&og[dst] = pb;
}

__global__ __launch_bounds__(512, 4) void attgate_psi(
    const float* __restrict__ x,
    const float* __restrict__ g,
    const uint16_t* __restrict__ Wxb,   // bf16 chunk layout [8][256][32]
    const uint16_t* __restrict__ Wgb,
    const float* __restrict__ Wpsi,
    const float* __restrict__ gamma,
    const float* __restrict__ beta,
    const float* __restrict__ bxg,
    const float* __restrict__ bpsi,
    float* __restrict__ psi_g)
{
    __shared__ __align__(16) ALds u;

    const int t    = threadIdx.x;
    const int lane = t & 63;
    const int wv   = t >> 6;        // wave 0..7
    const int os   = wv & 3;        // output-channel slice (x64)
    const int ps   = wv >> 2;       // pixel slice (x32), 0..1
    const int ln   = lane & 15;
    const int q    = lane >> 4;     // k-quad 0..3

    const int gp0  = blockIdx.x * 64;            // global pixel base
    const int b    = gp0 >> 12;                  // batch (4096 px per image)
    const int pix0 = gp0 & 4095;
    const size_t xbase = (size_t)b * (256 * 4096) + pix0;  // + c*4096 + p

    // ---- A staging: thread = 1 pixel x 8 contiguous channels of every iter.
    // All 64 loads issued up-front (independent -> deep MLP), then packed to
    // bf16 and ds_write_b128'd. ONE barrier for the whole K-depth.
    const int at  = t & 255;
    const int px  = at & 63;
    const int cg  = at >> 6;        // 0..3
    const int c0  = cg * 8;
    const float* Asrc = (t < 256) ? x : g;
    const int tens    = (t < 256) ? 0 : 1;

    float av[64];
    #pragma unroll
    for (int it = 0; it < 8; ++it)
        #pragma unroll
        for (int c = 0; c < 8; ++c)
            av[it * 8 + c] = Asrc[xbase + (size_t)(it * 32 + c0 + c) * 4096 + px];

    uint16_t* dstrow = &u.a[tens][px * STR2];
    #pragma unroll
    for (int it = 0; it < 8; ++it) {
        uint4 w;
        w.x = (uint32_t)f2b(av[it*8+0]) | ((uint32_t)f2b(av[it*8+1]) << 16);
        w.y = (uint32_t)f2b(av[it*8+2]) | ((uint32_t)f2b(av[it*8+3]) << 16);
        w.z = (uint32_t)f2b(av[it*8+4]) | ((uint32_t)f2b(av[it*8+5]) << 16);
        w.w = (uint32_t)f2b(av[it*8+6]) | ((uint32_t)f2b(av[it*8+7]) << 16);
        *(uint4*)&dstrow[it * 32 + c0] = w;   // ds_write_b128, conflict-free
    }

    f32x4 acc[2][4];
    #pragma unroll
    for (int i = 0; i < 2; ++i)
        #pragma unroll
        for (int j = 0; j < 4; ++j)
            acc[i][j] = (f32x4){0.f, 0.f, 0.f, 0.f};

    const int fro = os * 64 + ln;   // W fragment row base offset

    __syncthreads();               // the ONLY pre-epilogue barrier

    #pragma unroll
    for (int it = 0; it < 8; ++it) {
        const uint16_t* Wxi = Wxb + it * 8192;
        const uint16_t* Wgi = Wgb + it * 8192;

        // B fragments for Wx (global, L2-hot, coalesced)
        bf16x8 bx[4];
        #pragma unroll
        for (int nt = 0; nt < 4; ++nt)
            bx[nt] = *(const bf16x8*)&Wxi[(fro + nt * 16) * 32 + q * 8];

        // A fragments (x) from LDS + MFMA x
        bf16x8 af[2];
        #pragma unroll
        for (int mt = 0; mt < 2; ++mt)
            af[mt] = *(const bf16x8*)&u.a[0][(ps * 32 + mt * 16 + ln) * STR2 + it * 32 + q * 8];
        #pragma unroll
        for (int mt = 0; mt < 2; ++mt)
            #pragma unroll
            for (int nt = 0; nt < 4; ++nt)
                acc[mt][nt] = __builtin_amdgcn_mfma_f32_16x16x32_bf16(af[mt], bx[nt], acc[mt][nt], 0, 0, 0);

        // B fragments for Wg + A fragments (g) + MFMA g
        bf16x8 bg[4];
        #pragma unroll
        for (int nt = 0; nt < 4; ++nt)
            bg[nt] = *(const bf16x8*)&Wgi[(fro + nt * 16) * 32 + q * 8];
        #pragma unroll
        for (int mt = 0; mt < 2; ++mt)
            af[mt] = *(const bf16x8*)&u.a[1][(ps * 32 + mt * 16 + ln) * STR2 + it * 32 + q * 8];
        #pragma unroll
        for (int mt = 0; mt < 2; ++mt)
            #pragma unroll
            for (int nt = 0; nt < 4; ++nt)
                acc[mt][nt] = __builtin_amdgcn_mfma_f32_16x16x32_bf16(af[mt], bg[nt], acc[mt][nt], 0, 0, 0);
    }

    __syncthreads();   // A LDS now reusable as epilogue scratch

    // ---- block-wide constants: sumA = sum(Wpsi*gamma), sumB = sum(Wpsi*beta) ----
    if (t < 256) {
        float a  = Wpsi[t] * gamma[t];
        float bb = Wpsi[t] * beta[t];
        #pragma unroll
        for (int off = 32; off; off >>= 1) {
            a  += __shfl_xor(a, off, 64);
            bb += __shfl_xor(bb, off, 64);
        }
        if (lane == 0) { u.e.cpart[wv] = a; u.e.cpart[4 + wv] = bb; }
    }

    // per-lane channel constants (channel o = os*64 + nt*16 + ln)
    float biasv[4], Ac[4];
    #pragma unroll
    for (int nt = 0; nt < 4; ++nt) {
        const int o = os * 64 + nt * 16 + ln;
        biasv[nt] = bxg[o];
        Ac[nt]    = Wpsi[o] * gamma[o];
    }
    __syncthreads();
    const float sumA = u.e.cpart[0] + u.e.cpart[1] + u.e.cpart[2] + u.e.cpart[3];
    const float sumB = u.e.cpart[4] + u.e.cpart[5] + u.e.cpart[6] + u.e.cpart[7];

    // ---- per-pixel reductions: s, ss, t over this wave's 64 channels ----
    #pragma unroll
    for (int mt = 0; mt < 2; ++mt) {
        #pragma unroll
        for (int r = 0; r < 4; ++r) {
            float s = 0.f, ss = 0.f, tt = 0.f;
            #pragma unroll
            for (int nt = 0; nt < 4; ++nt) {
                float v = acc[mt][nt][r] + biasv[nt];
                v = fmaxf(v, 0.f);               // relu
                s += v; ss += v * v; tt += Ac[nt] * v;
            }
            #pragma unroll
            for (int off = 1; off < 16; off <<= 1) {   // reduce 16 lanes (n dim)
                s  += __shfl_xor(s,  off, 64);
                ss += __shfl_xor(ss, off, 64);
                tt += __shfl_xor(tt, off, 64);
            }
            if (ln == 0) {
                const int pix = ps * 32 + mt * 16 + q * 4 + r;   // C/D row = q*4 + reg
                u.e.red[0][os][pix] = s;
                u.e.red[1][os][pix] = ss;
                u.e.red[2][os][pix] = tt;
            }
        }
    }
    __syncthreads();

    // ---- LN + psi dot + sigmoid -> psi (one thread per pixel) ----
    if (t < 64) {
        const float s  = u.e.red[0][0][t] + u.e.red[0][1][t] + u.e.red[0][2][t] + u.e.red[0][3][t];
        const float ss = u.e.red[1][0][t] + u.e.red[1][1][t] + u.e.red[1][2][t] + u.e.red[1][3][t];
        const float tt = u.e.red[2][0][t] + u.e.red[2][1][t] + u.e.red[2][2][t] + u.e.red[2][3][t];
        const float mu   = s * (1.f / 256.f);
        const float var  = ss * (1.f / 256.f) - mu * mu;
        const float rstd = rsqrtf(var + LN_EPS);
        const float z    = rstd * (tt - mu * sumA) + sumB + bpsi[0];
        psi_g[gp0 + t] = 1.f / (1.f + __expf(-z));
    }
}

// ---- out = psi * x, pure streaming ----
__global__ __launch_bounds__(256) void gate_mul(
    const float* __restrict__ x,
    const float* __restrict__ psi,
    float* __restrict__ out)
{
    const float4* __restrict__ x4  = (const float4*)x;
    float4* __restrict__ o4        = (float4*)out;
    int i = blockIdx.x * 256 + threadIdx.x;
    #pragma unroll 1
    for (; i < 4194304; i += 524288) {          // 16 images * 256 ch * 1024 f4
        const int b   = i >> 18;                // 262144 f4 per image
        const int rem = i & 262143;
        const int p4  = rem & 1023;             // f4 index within channel row
        const float4 pv = *(const float4*)&psi[(b << 12) + (p4 << 2)];
        const float4 xv = x4[i];
        float4 o;
        o.x = xv.x * pv.x; o.y = xv.y * pv.y; o.z = xv.z * pv.z; o.w = xv.w * pv.w;
        o4[i] = o;
    }
}

extern "C" void kernel_launch(void* const* d_in, const int* in_sizes, int n_in,
                              void* d_out, int out_size, void* d_ws, size_t ws_size,
                              hipStream_t stream) {
    const float* x    = (const float*)d_in[0];
    const float* g    = (const float*)d_in[1];
    const float* Wx   = (const float*)d_in[2];
    const float* Wg   = (const float*)d_in[3];
    const float* Wpsi = (const float*)d_in[4];
    const float* gam  = (const float*)d_in[5];
    const float* bet  = (const float*)d_in[6];
    const float* bxg  = (const float*)d_in[7];
    const float* bpsi = (const float*)d_in[8];
    float* out        = (float*)d_out;

    uint16_t* Wxb = (uint16_t*)d_ws;                       // 131072 B
    uint16_t* Wgb = (uint16_t*)((char*)d_ws + 131072);     // 131072 B
    float*    psi = (float*)((char*)d_ws + 262144);        // 262144 B

    wconv_kernel<<<dim3(64), dim3(256), 0, stream>>>(Wx, Wg, Wxb, Wgb);
    attgate_psi<<<dim3(1024), dim3(512), 0, stream>>>(
        x, g, Wxb, Wgb, Wpsi, gam, bet, bxg, bpsi, psi);
    gate_mul<<<dim3(2048), dim3(256), 0, stream>>>(x, psi, out);
}